// Round 11
// baseline (35.409 us; speedup 1.0000x reference)
//
#include <hip/hip_runtime.h>
#include <hip/hip_bf16.h>

#define C_IN 1024
#define T_SZ 128
#define CTX 64
#define NEV 16
#define BK 64
#define NTILE 16     // C_IN / BK
#define NTHR 512
#define BROW 72      // bf16 row stride (144 B: 16B-aligned, bank-uniform)
#define PLROW 132    // padded P dump row stride (f32 elems)

// arena layout (bytes)
#define BF_OFF 0                 // Bf: 2*128*72*2 = 36864
#define WB_OFF 36864             // Wb: 2*64*72*2  = 18432
#define WS_OFF 55296             // wswl: 1024*4   = 4096
#define SP_OFF 59392             // swp: 8*128*4   = 4096
#define AT_OFF 63488             // attn: 128*4
#define TV_OFF 64000             // topv
#define TI_OFF 64064             // topi
#define ARENA_SZ 64128

typedef short bf16x8 __attribute__((ext_vector_type(8)));
typedef float f32x4 __attribute__((ext_vector_type(4)));
typedef float f32x2 __attribute__((ext_vector_type(2)));

__device__ __forceinline__ unsigned short f2bf(float f) {
  __hip_bfloat16 h = __float2bfloat16(f);
  return *(unsigned short*)&h;
}

#define BARRIER() do { \
  asm volatile("s_waitcnt lgkmcnt(0)" ::: "memory"); \
  __builtin_amdgcn_s_barrier(); \
} while (0)

// load enc tile kt slice (8 c x 2 t per thread, coalesced 512B/instr, NT to skip L1)
// + W tile slice (cached: L2-resident, reused across blocks). kt may be runtime.
#define ISSUE(kt, ev, wv) do { \
  const float* _s = encB + (kt) * (BK * T_SZ) + cb0 * T_SZ + t0; \
  _Pragma("unroll") for (int _j = 0; _j < 8; ++_j) \
    ev[_j] = __builtin_nontemporal_load((const f32x2*)(_s + _j * T_SZ)); \
  const float* _w = wvec + wd * C_IN + (kt) * BK + wc; \
  wv[0] = *(const float4*)_w; \
  wv[1] = *(const float4*)(_w + 4); \
} while (0)

// switch partial (exact f32) + convert to bf16 + write B/W fragments to LDS
#define CONVERT(kt, ev, wv, buf) do { \
  const float* _wt = wswl + (kt) * BK + cb0; \
  union { bf16x8 v; unsigned short u[8]; } _p0, _p1, _pw; \
  _Pragma("unroll") for (int _j = 0; _j < 8; ++_j) { \
    sw0 = fmaf(ev[_j].x, _wt[_j], sw0); \
    sw1 = fmaf(ev[_j].y, _wt[_j], sw1); \
    _p0.u[_j] = f2bf(ev[_j].x); \
    _p1.u[_j] = f2bf(ev[_j].y); \
  } \
  *(bf16x8*)&Bf[((buf) * T_SZ + t0) * BROW + cb0] = _p0.v; \
  *(bf16x8*)&Bf[((buf) * T_SZ + t0 + 1) * BROW + cb0] = _p1.v; \
  _pw.u[0] = f2bf(wv[0].x); _pw.u[1] = f2bf(wv[0].y); \
  _pw.u[2] = f2bf(wv[0].z); _pw.u[3] = f2bf(wv[0].w); \
  _pw.u[4] = f2bf(wv[1].x); _pw.u[5] = f2bf(wv[1].y); \
  _pw.u[6] = f2bf(wv[1].z); _pw.u[7] = f2bf(wv[1].w); \
  *(bf16x8*)&Wb[((buf) * CTX + wd) * BROW + wc] = _pw.v; \
} while (0)

#define MFMA_TILE(buf) do { \
  _Pragma("unroll") for (int _ks = 0; _ks < 2; ++_ks) { \
    bf16x8 _bv = *(const bf16x8*)&Bf[((buf) * T_SZ + n0 + tl) * BROW + _ks * 32 + g * 8]; \
    bf16x8 _a0 = *(const bf16x8*)&Wb[((buf) * CTX +  0 + tl) * BROW + _ks * 32 + g * 8]; \
    bf16x8 _a1 = *(const bf16x8*)&Wb[((buf) * CTX + 16 + tl) * BROW + _ks * 32 + g * 8]; \
    bf16x8 _a2 = *(const bf16x8*)&Wb[((buf) * CTX + 32 + tl) * BROW + _ks * 32 + g * 8]; \
    bf16x8 _a3 = *(const bf16x8*)&Wb[((buf) * CTX + 48 + tl) * BROW + _ks * 32 + g * 8]; \
    acc0 = __builtin_amdgcn_mfma_f32_16x16x32_bf16(_a0, _bv, acc0, 0, 0, 0); \
    acc1 = __builtin_amdgcn_mfma_f32_16x16x32_bf16(_a1, _bv, acc1, 0, 0, 0); \
    acc2 = __builtin_amdgcn_mfma_f32_16x16x32_bf16(_a2, _bv, acc2, 0, 0, 0); \
    acc3 = __builtin_amdgcn_mfma_f32_16x16x32_bf16(_a3, _bv, acc3, 0, 0, 0); \
  } } while (0)

// pipeline step with per-block tile-order rotation (s0): logical tile T maps to
// physical tile (T+s0)&15. LDS bufs indexed by LOGICAL pipeline position.
#define STEP(T, SI, SC) do { \
  if ((T) + 3 < NTILE) ISSUE(((T) + 3 + s0) & 15, ev##SI, wv##SI); \
  MFMA_TILE((T) & 1); \
  if ((T) + 1 < NTILE) CONVERT(((T) + 1 + s0) & 15, ev##SC, wv##SC, ((T) + 1) & 1); \
  BARRIER(); \
} while (0)

__global__ __launch_bounds__(NTHR, 1) void fused_sparsify(
    const float* __restrict__ enc,   // [256][1024][128] f32
    const float* __restrict__ wvec,  // [64][1024] f32
    const float* __restrict__ bvec,  // [64] f32
    const float* __restrict__ wsw,   // [1024] f32
    const float* __restrict__ bsw,   // [1] f32
    float* __restrict__ out)         // vecs [256*16*64] ++ sched [256*16*128], f32
{
  const int b    = blockIdx.x;
  const int tid  = threadIdx.x;
  const int lane = tid & 63;
  const int wid  = tid >> 6;   // wave 0..7
  const int g    = lane >> 4;  // k-group 0..3
  const int tl   = lane & 15;
  const int n0   = wid * 16;   // this wave's MFMA t-slice
  const int s0   = b & 15;     // per-block K-tile phase rotation

  // staging geometry: wave = c-block of 8, lane = t-pair
  const int cb0 = wid * 8;     // c offset within tile
  const int t0  = 2 * lane;    // t pair
  const int wd  = tid >> 3;    // W row 0..63
  const int wc  = (tid & 7) * 8;

  __shared__ __align__(16) char arena[ARENA_SZ];
  unsigned short* Bf = (unsigned short*)(arena + BF_OFF);  // [2][128][BROW] bf16
  unsigned short* Wb = (unsigned short*)(arena + WB_OFF);  // [2][64][BROW] bf16
  float* wswl = (float*)(arena + WS_OFF);
  float* swp  = (float*)(arena + SP_OFF);                  // [8][128]
  float* attn = (float*)(arena + AT_OFF);
  float* topv = (float*)(arena + TV_OFF);
  int*   topi = (int*)(arena + TI_OFF);

  const float* encB = enc + (size_t)b * (C_IN * T_SZ);

  f32x4 acc0 = {0.f, 0.f, 0.f, 0.f};
  f32x4 acc1 = acc0, acc2 = acc0, acc3 = acc0;
  float sw0 = 0.f, sw1 = 0.f;

  f32x2 evA[8], evB[8], evC[8];
  float4 wvA[2], wvB[2], wvC[2];

  // ---------- prologue: 3 tiles in flight (rotated) ----------
  ISSUE((0 + s0) & 15, evA, wvA);
  ISSUE((1 + s0) & 15, evB, wvB);
  ISSUE((2 + s0) & 15, evC, wvC);
  wswl[tid]       = wsw[tid];
  wswl[tid + 512] = wsw[tid + 512];
  BARRIER();                 // publish wswl (tile loads stay in flight)
  CONVERT((0 + s0) & 15, evA, wvA, 0);
  BARRIER();                 // publish Bf[0], Wb[0]

  // ---------- 16 fully-unrolled steps, slot = t%3, buf = t&1 ----------
  STEP( 0, A, B); STEP( 1, B, C); STEP( 2, C, A);
  STEP( 3, A, B); STEP( 4, B, C); STEP( 5, C, A);
  STEP( 6, A, B); STEP( 7, B, C); STEP( 8, C, A);
  STEP( 9, A, B); STEP(10, B, C); STEP(11, C, A);
  STEP(12, A, B); STEP(13, B, C); STEP(14, C, A);
  MFMA_TILE(1);              // logical tile 15
  BARRIER();                 // protect Bf before P-dump overlay

  // ---------- epilogue: P dump (overlays Bf, dead) + switch partials ----------
  float* Pl = (float*)(arena + BF_OFF);    // [64][PLROW] f32 = 33792 B
#pragma unroll
  for (int r = 0; r < 4; ++r) {
    Pl[( 0 + 4 * g + r) * PLROW + n0 + tl] = acc0[r];
    Pl[(16 + 4 * g + r) * PLROW + n0 + tl] = acc1[r];
    Pl[(32 + 4 * g + r) * PLROW + n0 + tl] = acc2[r];
    Pl[(48 + 4 * g + r) * PLROW + n0 + tl] = acc3[r];
  }
  swp[wid * T_SZ + t0]     = sw0;
  swp[wid * T_SZ + t0 + 1] = sw1;
  __syncthreads();

  if (tid < T_SZ) {
    float s = 0.f;
#pragma unroll
    for (int k = 0; k < 8; ++k) s += swp[k * T_SZ + tid];
    attn[tid] = fmaxf(s + bsw[0], 0.f);
  }
  __syncthreads();

  // ---------- top-16 descending, ties -> lower index (wave 0) ----------
  if (tid < 64) {
    float v0 = attn[tid], v1 = attn[tid + 64];
#pragma unroll 1
    for (int r = 0; r < NEV; ++r) {
      float bv; int bi;
      if (v0 >= v1) { bv = v0; bi = tid; } else { bv = v1; bi = tid + 64; }
#pragma unroll
      for (int off = 32; off > 0; off >>= 1) {
        float ov = __shfl_xor(bv, off, 64);
        int   oi = __shfl_xor(bi, off, 64);
        if (ov > bv || (ov == bv && oi < bi)) { bv = ov; bi = oi; }
      }
      if (bi == tid) v0 = -__builtin_inff();
      if (bi == tid + 64) v1 = -__builtin_inff();
      if (tid == r) { topv[r] = bv; topi[r] = bi; }
    }
  }
  __syncthreads();

  // ---------- scheduling: out[262144 + b*2048 + j*128 + t] ----------
  {
    float* os = out + (256 * NEV * CTX) + b * (NEV * T_SZ);
    int j  = tid >> 5;
    int tt = (tid * 4) & 127;
    float tv = topv[j];
    int   ti = topi[j];
    float4 v;
    v.x = (tt + 0 == ti) ? tv : 0.f;
    v.y = (tt + 1 == ti) ? tv : 0.f;
    v.z = (tt + 2 == ti) ? tv : 0.f;
    v.w = (tt + 3 == ti) ? tv : 0.f;
    *(float4*)&os[tid * 4] = v;
  }
  // ---------- vecs: out[b*1024 + j*64 + d] = P[d][idx[j]] + b_vec[d] ----------
  {
    float* ov = out + b * (NEV * CTX);
#pragma unroll
    for (int s = 0; s < 2; ++s) {
      int o = s * NTHR + tid;
      int j = o >> 6, d = o & 63;
      ov[o] = Pl[d * PLROW + topi[j]] + bvec[d];
    }
  }
}

extern "C" void kernel_launch(void* const* d_in, const int* in_sizes, int n_in,
                              void* d_out, int out_size, void* d_ws, size_t ws_size,
                              hipStream_t stream) {
  const float* enc  = (const float*)d_in[0];
  const float* wvec = (const float*)d_in[1];
  const float* bvec = (const float*)d_in[2];
  const float* wsw  = (const float*)d_in[3];
  const float* bsw  = (const float*)d_in[4];
  float* o = (float*)d_out;
  (void)in_sizes; (void)n_in; (void)out_size; (void)d_ws; (void)ws_size;
  fused_sparsify<<<256, NTHR, 0, stream>>>(enc, wvec, bvec, wsw, bsw, o);
}